// Round 1
// baseline (1629.132 us; speedup 1.0000x reference)
//
#include <hip/hip_runtime.h>
#include <hip/hip_bf16.h>
#include <stdint.h>

// VectorQuantizer: N=65536 keys[N,64] f32, K=4096 embeddings[K,64] f32.
// out = concat(samples[N,64], log_probs[N,4096]) f32.
// samples = keys + (emb[argmax(logits + gumbel)] - keys)  (forward value),
// logits = 2*keys@emb.T - |k|^2 - |e|^2, gumbel = jax threefry2x32(key(1)).
//
// Exactness-critical: argmax index (samples tol ~0.2% of data scale).
//   -> sequential-FMA dots (BLAS k-order), numpy pairwise-8 row norms,
//      __f*_rn ops (hip default -ffp-contract=fast would fuse otherwise),
//      exact threefry (integer), precise logf for gumbel.
// Tolerance-lenient: log_probs (abs tol 0.21875) -> lse precomputed by a
//   bf16 MFMA GEMM + fused row-sumexp kernel (err ~0.02 << tol), letting the
//   exact kernel write l - lse[n] in a single pass (no logits store/reload).

#define NROWS 65536
#define KCODES 4096
#define NPAIR 32768
#define LP_OFF 4194304ull  // 65536*64

typedef float f32x4_t __attribute__((ext_vector_type(4)));
typedef short s16x8_t __attribute__((ext_vector_type(8)));

__device__ __forceinline__ uint32_t rotl32(uint32_t x, int r) {
  return (x << r) | (x >> (32 - r));
}

// jax threefry2x32-20, key = (0,1)  (jax.random.key(1))
__device__ __forceinline__ void threefry(uint32_t x0, uint32_t x1,
                                         uint32_t& o0, uint32_t& o1) {
  const uint32_t k0 = 0u, k1 = 1u, k2 = 0x1BD11BDBu;  // 0^1^0x1BD11BDA
  x0 += k0; x1 += k1;
  // group 1: rot 13,15,26,6
  x0 += x1; x1 = rotl32(x1, 13); x1 ^= x0;
  x0 += x1; x1 = rotl32(x1, 15); x1 ^= x0;
  x0 += x1; x1 = rotl32(x1, 26); x1 ^= x0;
  x0 += x1; x1 = rotl32(x1, 6);  x1 ^= x0;
  x0 += k1; x1 += k2 + 1u;
  // group 2: 17,29,16,24
  x0 += x1; x1 = rotl32(x1, 17); x1 ^= x0;
  x0 += x1; x1 = rotl32(x1, 29); x1 ^= x0;
  x0 += x1; x1 = rotl32(x1, 16); x1 ^= x0;
  x0 += x1; x1 = rotl32(x1, 24); x1 ^= x0;
  x0 += k2; x1 += k0 + 2u;
  // group 3: 13,15,26,6
  x0 += x1; x1 = rotl32(x1, 13); x1 ^= x0;
  x0 += x1; x1 = rotl32(x1, 15); x1 ^= x0;
  x0 += x1; x1 = rotl32(x1, 26); x1 ^= x0;
  x0 += x1; x1 = rotl32(x1, 6);  x1 ^= x0;
  x0 += k0; x1 += k1 + 3u;
  // group 4: 17,29,16,24
  x0 += x1; x1 = rotl32(x1, 17); x1 ^= x0;
  x0 += x1; x1 = rotl32(x1, 29); x1 ^= x0;
  x0 += x1; x1 = rotl32(x1, 16); x1 ^= x0;
  x0 += x1; x1 = rotl32(x1, 24); x1 ^= x0;
  x0 += k1; x1 += k2 + 4u;
  // group 5: 13,15,26,6
  x0 += x1; x1 = rotl32(x1, 13); x1 ^= x0;
  x0 += x1; x1 = rotl32(x1, 15); x1 ^= x0;
  x0 += x1; x1 = rotl32(x1, 26); x1 ^= x0;
  x0 += x1; x1 = rotl32(x1, 6);  x1 ^= x0;
  x0 += k2; x1 += k0 + 5u;
  o0 = x0; o1 = x1;
}

// jax gumbel from raw bits: u in [tiny,1), g = -log(-log(u))
__device__ __forceinline__ float gumbel_bits(uint32_t b) {
  float f = __fsub_rn(__uint_as_float(0x3f800000u | (b >> 9)), 1.0f);
  float u = fmaxf(f, 1.17549435e-38f);
  return -logf(-logf(u));
}

__device__ __forceinline__ unsigned short f2bf(float x) {
  uint32_t u = __float_as_uint(x);
  uint32_t r = (u + 0x7fffu + ((u >> 16) & 1u)) >> 16;  // RNE
  return (unsigned short)r;
}

// ---------------- K0: per-code norms (numpy pairwise-8 exact) + bf16 copy ---
__global__ void vq_pre(const float* __restrict__ emb, float* __restrict__ t_ws,
                       unsigned short* __restrict__ e16) {
  int row = blockIdx.x * 256 + threadIdx.x;
  if (row >= KCODES) return;
  const float* e = emb + (size_t)row * 64;
  float v[64];
#pragma unroll
  for (int i = 0; i < 64; ++i) v[i] = e[i];
  float r[8];
#pragma unroll
  for (int j = 0; j < 8; ++j) r[j] = __fmul_rn(v[j], v[j]);
#pragma unroll
  for (int m = 1; m < 8; ++m) {
#pragma unroll
    for (int j = 0; j < 8; ++j) r[j] = __fadd_rn(r[j], __fmul_rn(v[m * 8 + j], v[m * 8 + j]));
  }
  t_ws[row] = __fadd_rn(__fadd_rn(__fadd_rn(r[0], r[1]), __fadd_rn(r[2], r[3])),
                        __fadd_rn(__fadd_rn(r[4], r[5]), __fadd_rn(r[6], r[7])));
  unsigned short* o = e16 + (size_t)row * 64;
#pragma unroll
  for (int i = 0; i < 64; ++i) o[i] = f2bf(v[i]);
}

// ---------------- K1: lse[n] via bf16 MFMA GEMM + fused row-sumexp ---------
// wave: 16 rows; A frag 16x16x32_bf16: lane -> row=lane&15, k=(lane>>4)*8+j
// C/D: col=lane&15, row=(lane>>4)*4+reg  [m89-verified layout]
__global__ __launch_bounds__(256) void vq_lse(const float* __restrict__ keys,
                                              const unsigned short* __restrict__ e16,
                                              const float* __restrict__ t_ws,
                                              float* __restrict__ lse_ws) {
  const int tid = threadIdx.x;
  const int w = tid >> 6, lane = tid & 63;
  const int r0 = blockIdx.x * 64 + w * 16;
  const int mrow = lane & 15, kg = lane >> 4;

  const float* ka = keys + (size_t)(r0 + mrow) * 64 + kg * 8;
  float av[16];
#pragma unroll
  for (int i = 0; i < 8; ++i) av[i] = ka[i];
#pragma unroll
  for (int i = 0; i < 8; ++i) av[8 + i] = ka[32 + i];
  float sp = 0.f;
#pragma unroll
  for (int i = 0; i < 16; ++i) sp = fmaf(av[i], av[i], sp);
  sp += __shfl_xor(sp, 16);
  sp += __shfl_xor(sp, 32);  // sp = |keys[r0+mrow]|^2 (approx ok: lse only)

  s16x8_t a0, a1;
#pragma unroll
  for (int i = 0; i < 8; ++i) { a0[i] = (short)f2bf(av[i]); a1[i] = (short)f2bf(av[8 + i]); }

  float S0 = 0.f, S1 = 0.f, S2 = 0.f, S3 = 0.f;
  for (int ct = 0; ct < 256; ++ct) {
    const int col = ct * 16 + mrow;
    const s16x8_t b0 = *(const s16x8_t*)(e16 + (size_t)col * 64 + kg * 8);
    const s16x8_t b1 = *(const s16x8_t*)(e16 + (size_t)col * 64 + 32 + kg * 8);
    f32x4_t acc = {0.f, 0.f, 0.f, 0.f};
    acc = __builtin_amdgcn_mfma_f32_16x16x32_bf16(a0, b0, acc, 0, 0, 0);
    acc = __builtin_amdgcn_mfma_f32_16x16x32_bf16(a1, b1, acc, 0, 0, 0);
    const float tc = t_ws[col];
    S0 += __expf(2.f * acc[0] - tc);
    S1 += __expf(2.f * acc[1] - tc);
    S2 += __expf(2.f * acc[2] - tc);
    S3 += __expf(2.f * acc[3] - tc);
  }
#pragma unroll
  for (int m = 1; m <= 8; m <<= 1) {
    S0 += __shfl_xor(S0, m); S1 += __shfl_xor(S1, m);
    S2 += __shfl_xor(S2, m); S3 += __shfl_xor(S3, m);
  }
  // s_n for rows kg*4+jj lives (post-reduce) at lane index kg*4+jj
  float s0 = __shfl(sp, kg * 4 + 0);
  float s1 = __shfl(sp, kg * 4 + 1);
  float s2 = __shfl(sp, kg * 4 + 2);
  float s3 = __shfl(sp, kg * 4 + 3);
  if (mrow == 0) {
    // lse = log(sum_k exp(2d - t_k)) - s_n   (exact shift identity)
    lse_ws[r0 + kg * 4 + 0] = logf(S0) - s0;
    lse_ws[r0 + kg * 4 + 1] = logf(S1) - s1;
    lse_ws[r0 + kg * 4 + 2] = logf(S2) - s2;
    lse_ws[r0 + kg * 4 + 3] = logf(S3) - s3;
  }
}

// ---------------- K2: exact logits + gumbel argmax + outputs ---------------
// lane: pair pi=lane>>2 (16/wave), stripe g=lane&3; pair p handles rows p and
// p+32768 (threefry counter pair (j, j+2^27), one call -> both rows' bits).
// k(s) = 4*s + g; per step the 4 stripe lanes of a pair write 16B contiguous.
__global__ __launch_bounds__(256, 2) void vq_main(const float* __restrict__ keys,
                                                  const float* __restrict__ emb,
                                                  const float* __restrict__ t_ws,
                                                  const float* __restrict__ lse_ws,
                                                  float* __restrict__ out) {
  __shared__ float4 ebuf[2][1024];  // 64 k-rows x 16 chunks, XOR-swizzled
  __shared__ float tbuf[2][64];

  const int tid = threadIdx.x;
  const int lane = tid & 63;
  const int w = tid >> 6;
  const int g = lane & 3;
  const int pi = lane >> 2;
  const int p = blockIdx.x * 64 + w * 16 + pi;
  const int nlo = p, nhi = p + NPAIR;

  float4 klo4[16], khi4[16];
  {
    const float4* kp0 = (const float4*)(keys + (size_t)nlo * 64);
    const float4* kp1 = (const float4*)(keys + (size_t)nhi * 64);
#pragma unroll
    for (int c = 0; c < 16; ++c) { klo4[c] = kp0[c]; khi4[c] = kp1[c]; }
  }

  // exact numpy pairwise-8 |k|^2 (element i=c*4+e: j=i%8 -> (c&1)*4+e, m=c>>1)
  float s_lo, s_hi;
  {
    float r0, r1, r2, r3, r4, r5, r6, r7;
    float4 a = klo4[0], b = klo4[1];
    r0 = __fmul_rn(a.x, a.x); r1 = __fmul_rn(a.y, a.y);
    r2 = __fmul_rn(a.z, a.z); r3 = __fmul_rn(a.w, a.w);
    r4 = __fmul_rn(b.x, b.x); r5 = __fmul_rn(b.y, b.y);
    r6 = __fmul_rn(b.z, b.z); r7 = __fmul_rn(b.w, b.w);
#pragma unroll
    for (int m = 1; m < 8; ++m) {
      a = klo4[2 * m]; b = klo4[2 * m + 1];
      r0 = __fadd_rn(r0, __fmul_rn(a.x, a.x)); r1 = __fadd_rn(r1, __fmul_rn(a.y, a.y));
      r2 = __fadd_rn(r2, __fmul_rn(a.z, a.z)); r3 = __fadd_rn(r3, __fmul_rn(a.w, a.w));
      r4 = __fadd_rn(r4, __fmul_rn(b.x, b.x)); r5 = __fadd_rn(r5, __fmul_rn(b.y, b.y));
      r6 = __fadd_rn(r6, __fmul_rn(b.z, b.z)); r7 = __fadd_rn(r7, __fmul_rn(b.w, b.w));
    }
    s_lo = __fadd_rn(__fadd_rn(__fadd_rn(r0, r1), __fadd_rn(r2, r3)),
                     __fadd_rn(__fadd_rn(r4, r5), __fadd_rn(r6, r7)));
    a = khi4[0]; b = khi4[1];
    r0 = __fmul_rn(a.x, a.x); r1 = __fmul_rn(a.y, a.y);
    r2 = __fmul_rn(a.z, a.z); r3 = __fmul_rn(a.w, a.w);
    r4 = __fmul_rn(b.x, b.x); r5 = __fmul_rn(b.y, b.y);
    r6 = __fmul_rn(b.z, b.z); r7 = __fmul_rn(b.w, b.w);
#pragma unroll
    for (int m = 1; m < 8; ++m) {
      a = khi4[2 * m]; b = khi4[2 * m + 1];
      r0 = __fadd_rn(r0, __fmul_rn(a.x, a.x)); r1 = __fadd_rn(r1, __fmul_rn(a.y, a.y));
      r2 = __fadd_rn(r2, __fmul_rn(a.z, a.z)); r3 = __fadd_rn(r3, __fmul_rn(a.w, a.w));
      r4 = __fadd_rn(r4, __fmul_rn(b.x, b.x)); r5 = __fadd_rn(r5, __fmul_rn(b.y, b.y));
      r6 = __fadd_rn(r6, __fmul_rn(b.z, b.z)); r7 = __fadd_rn(r7, __fmul_rn(b.w, b.w));
    }
    s_hi = __fadd_rn(__fadd_rn(__fadd_rn(r0, r1), __fadd_rn(r2, r3)),
                     __fadd_rn(__fadd_rn(r4, r5), __fadd_rn(r6, r7)));
  }

  const float lse_lo = lse_ws[nlo], lse_hi = lse_ws[nhi];

  float best_lo = -__builtin_inff(), best_hi = -__builtin_inff();
  int bi_lo = 0, bi_hi = 0;

  float* olo = out + LP_OFF + (size_t)nlo * KCODES;
  float* ohi = out + LP_OFF + (size_t)nhi * KCODES;

  // stage tile 0 (rows 0..63); LDS linear dest, source chunk XOR-swizzled
#pragma unroll
  for (int it = 0; it < 4; ++it) {
    const int q = it * 256 + tid;
    const int rr = q >> 4, cc = q & 15, gc = cc ^ (rr & 15);
    ebuf[0][q] = *(const float4*)(emb + (size_t)rr * 64 + gc * 4);
  }
  if (tid < 64) tbuf[0][tid] = t_ws[tid];
  __syncthreads();

  const uint32_t jbase = (uint32_t)p * 4096u + (uint32_t)g;

  for (int T = 0; T < 64; ++T) {
    const int cur = T & 1;
    float4 st0, st1, st2, st3;
    float stt = 0.f;
    const bool hasNext = (T + 1 < 64);
    if (hasNext) {  // issue loads now; LDS write deferred past compute (T14)
      const size_t rbase = (size_t)(T + 1) * 64;
      {
        const int q = tid;              const int rr = q >> 4, gc = (q & 15) ^ (rr & 15);
        st0 = *(const float4*)(emb + (rbase + rr) * 64 + gc * 4);
      }
      {
        const int q = 256 + tid;        const int rr = q >> 4, gc = (q & 15) ^ (rr & 15);
        st1 = *(const float4*)(emb + (rbase + rr) * 64 + gc * 4);
      }
      {
        const int q = 512 + tid;        const int rr = q >> 4, gc = (q & 15) ^ (rr & 15);
        st2 = *(const float4*)(emb + (rbase + rr) * 64 + gc * 4);
      }
      {
        const int q = 768 + tid;        const int rr = q >> 4, gc = (q & 15) ^ (rr & 15);
        st3 = *(const float4*)(emb + (rbase + rr) * 64 + gc * 4);
      }
      if (tid < 64) stt = t_ws[(T + 1) * 64 + tid];
    }

#pragma unroll 1
    for (int s = 0; s < 16; ++s) {
      const int row = s * 4 + g;
      const float4* rowb = &ebuf[cur][row * 16];
      const int rx = row & 15;
      const float tk = tbuf[cur][row];
      float dlo = 0.f, dhi = 0.f;
#pragma unroll
      for (int c = 0; c < 16; ++c) {
        const float4 e = rowb[c ^ rx];
        const float4 kl = klo4[c];
        const float4 kh = khi4[c];
        dlo = __builtin_fmaf(kl.x, e.x, dlo);
        dhi = __builtin_fmaf(kh.x, e.x, dhi);
        dlo = __builtin_fmaf(kl.y, e.y, dlo);
        dhi = __builtin_fmaf(kh.y, e.y, dhi);
        dlo = __builtin_fmaf(kl.z, e.z, dlo);
        dhi = __builtin_fmaf(kh.z, e.z, dhi);
        dlo = __builtin_fmaf(kl.w, e.w, dlo);
        dhi = __builtin_fmaf(kh.w, e.w, dhi);
      }
      const float llo = __fsub_rn(__fsub_rn(__fmul_rn(2.0f, dlo), s_lo), tk);
      const float lhi = __fsub_rn(__fsub_rn(__fmul_rn(2.0f, dhi), s_hi), tk);

      const int k = T * 64 + row;
      const uint32_t j = jbase + (uint32_t)(T * 64 + s * 4);
      uint32_t o0, o1;
      threefry(j, j + 0x08000000u, o0, o1);
      const float vlo = __fadd_rn(llo, gumbel_bits(o0));
      const float vhi = __fadd_rn(lhi, gumbel_bits(o1));
      if (vlo > best_lo) { best_lo = vlo; bi_lo = k; }
      if (vhi > best_hi) { best_hi = vhi; bi_hi = k; }
      olo[k] = __fsub_rn(llo, lse_lo);
      ohi[k] = __fsub_rn(lhi, lse_hi);
    }

    if (hasNext) {
      const int nxt = (T + 1) & 1;
      ebuf[nxt][tid] = st0;
      ebuf[nxt][256 + tid] = st1;
      ebuf[nxt][512 + tid] = st2;
      ebuf[nxt][768 + tid] = st3;
      if (tid < 64) tbuf[nxt][tid] = stt;
    }
    __syncthreads();
  }

  // argmax across the pair's 4 stripe lanes; first-index tiebreak
#pragma unroll
  for (int m = 1; m <= 2; m <<= 1) {
    float ov = __shfl_xor(best_lo, m);
    int oi = __shfl_xor(bi_lo, m);
    if (ov > best_lo || (ov == best_lo && oi < bi_lo)) { best_lo = ov; bi_lo = oi; }
    ov = __shfl_xor(best_hi, m);
    oi = __shfl_xor(bi_hi, m);
    if (ov > best_hi || (ov == best_hi && oi < bi_hi)) { best_hi = ov; bi_hi = oi; }
  }

  // samples = k + (q - k), exact op order; lane g writes chunks c with c>>2==g
  float* slo = out + (size_t)nlo * 64;
  float* shi = out + (size_t)nhi * 64;
  const float* eblo = emb + (size_t)bi_lo * 64;
  const float* ebhi = emb + (size_t)bi_hi * 64;
#pragma unroll
  for (int c = 0; c < 16; ++c) {
    if ((c >> 2) == g) {
      float4 q0 = *(const float4*)(eblo + c * 4);
      float4 kk = klo4[c];
      float4 r;
      r.x = __fadd_rn(kk.x, __fsub_rn(q0.x, kk.x));
      r.y = __fadd_rn(kk.y, __fsub_rn(q0.y, kk.y));
      r.z = __fadd_rn(kk.z, __fsub_rn(q0.z, kk.z));
      r.w = __fadd_rn(kk.w, __fsub_rn(q0.w, kk.w));
      *(float4*)(slo + c * 4) = r;
      float4 q1 = *(const float4*)(ebhi + c * 4);
      kk = khi4[c];
      r.x = __fadd_rn(kk.x, __fsub_rn(q1.x, kk.x));
      r.y = __fadd_rn(kk.y, __fsub_rn(q1.y, kk.y));
      r.z = __fadd_rn(kk.z, __fsub_rn(q1.z, kk.z));
      r.w = __fadd_rn(kk.w, __fsub_rn(q1.w, kk.w));
      *(float4*)(shi + c * 4) = r;
    }
  }
}

extern "C" void kernel_launch(void* const* d_in, const int* in_sizes, int n_in,
                              void* d_out, int out_size, void* d_ws, size_t ws_size,
                              hipStream_t stream) {
  const float* keys = (const float*)d_in[0];
  const float* emb = (const float*)d_in[1];
  float* out = (float*)d_out;
  char* w = (char*)d_ws;
  float* t_ws = (float*)w;                                   // 4096 f32
  unsigned short* e16 = (unsigned short*)(w + 16384);        // 4096*64 bf16
  float* lse_ws = (float*)(w + 16384 + 524288);              // 65536 f32

  vq_pre<<<16, 256, 0, stream>>>(emb, t_ws, e16);
  vq_lse<<<1024, 256, 0, stream>>>(keys, e16, t_ws, lse_ws);
  vq_main<<<512, 256, 0, stream>>>(keys, emb, t_ws, lse_ws, out);
}

// Round 2
// 955.588 us; speedup vs baseline: 1.7048x; 1.7048x over previous
//
#include <hip/hip_runtime.h>
#include <hip/hip_bf16.h>
#include <stdint.h>

// VectorQuantizer: N=65536 keys[N,64] f32, K=4096 emb[K,64] f32.
// out = concat(samples[N,64], log_probs[N,4096]) f32.
//
// Round-2: vq_main rebuilt around split-bf16 MFMA (3-way split, 6 terms ->
// d accurate ~1e-7, same class as any f32 GEMM; reference's l is quantized
// at ulp(64)=4e-6 by the -s step, so flip risk ~1-2%). No LDS, no barriers;
// B fragments pre-swizzled in ws and streamed from L2. Stores coalesce in
// 64B sectors. threefry/gumbel/tiebreak kept bit-identical to round-1.

#define NROWS 65536
#define KCODES 4096
#define NPAIR 32768
#define LP_OFF 4194304ull  // 65536*64

// ws byte offsets
#define WS_T 0u
#define WS_S 65536u
#define WS_LSE 327680u
#define WS_E16 589824u
#define WS_B 1114112u

typedef float f32x4_t __attribute__((ext_vector_type(4)));
typedef short s16x8_t __attribute__((ext_vector_type(8)));

__device__ __forceinline__ uint32_t rotl32(uint32_t x, int r) {
  return (x << r) | (x >> (32 - r));
}

// jax threefry2x32-20, key = (0,1)  (jax.random.key(1)) -- verified round-1
__device__ __forceinline__ void threefry(uint32_t x0, uint32_t x1,
                                         uint32_t& o0, uint32_t& o1) {
  const uint32_t k0 = 0u, k1 = 1u, k2 = 0x1BD11BDBu;
  x0 += k0; x1 += k1;
  x0 += x1; x1 = rotl32(x1, 13); x1 ^= x0;
  x0 += x1; x1 = rotl32(x1, 15); x1 ^= x0;
  x0 += x1; x1 = rotl32(x1, 26); x1 ^= x0;
  x0 += x1; x1 = rotl32(x1, 6);  x1 ^= x0;
  x0 += k1; x1 += k2 + 1u;
  x0 += x1; x1 = rotl32(x1, 17); x1 ^= x0;
  x0 += x1; x1 = rotl32(x1, 29); x1 ^= x0;
  x0 += x1; x1 = rotl32(x1, 16); x1 ^= x0;
  x0 += x1; x1 = rotl32(x1, 24); x1 ^= x0;
  x0 += k2; x1 += k0 + 2u;
  x0 += x1; x1 = rotl32(x1, 13); x1 ^= x0;
  x0 += x1; x1 = rotl32(x1, 15); x1 ^= x0;
  x0 += x1; x1 = rotl32(x1, 26); x1 ^= x0;
  x0 += x1; x1 = rotl32(x1, 6);  x1 ^= x0;
  x0 += k0; x1 += k1 + 3u;
  x0 += x1; x1 = rotl32(x1, 17); x1 ^= x0;
  x0 += x1; x1 = rotl32(x1, 29); x1 ^= x0;
  x0 += x1; x1 = rotl32(x1, 16); x1 ^= x0;
  x0 += x1; x1 = rotl32(x1, 24); x1 ^= x0;
  x0 += k1; x1 += k2 + 4u;
  x0 += x1; x1 = rotl32(x1, 13); x1 ^= x0;
  x0 += x1; x1 = rotl32(x1, 15); x1 ^= x0;
  x0 += x1; x1 = rotl32(x1, 26); x1 ^= x0;
  x0 += x1; x1 = rotl32(x1, 6);  x1 ^= x0;
  x0 += k2; x1 += k0 + 5u;
  o0 = x0; o1 = x1;
}

// jax gumbel from raw bits (precise logf both levels -- verified round-1)
__device__ __forceinline__ float gumbel_bits(uint32_t b) {
  float f = __fsub_rn(__uint_as_float(0x3f800000u | (b >> 9)), 1.0f);
  float u = fmaxf(f, 1.17549435e-38f);
  return -logf(-logf(u));
}

__device__ __forceinline__ unsigned short f2bf(float x) {
  uint32_t u = __float_as_uint(x);
  uint32_t r = (u + 0x7fffu + ((u >> 16) & 1u)) >> 16;  // RNE
  return (unsigned short)r;
}
__device__ __forceinline__ float bf2f(unsigned short u) {
  return __uint_as_float((uint32_t)u << 16);
}

// ---- K0: per-code |e|^2 (numpy pairwise-8), e16 row-major, B fragments ----
// B frag layout (ushort idx): ((ct*6 + s*2 + h)*64 + kg*16 + col)*8 + j
//   value = split_s( emb[ct*16+col][h*32 + kg*8 + j] )
__global__ void vq_pre(const float* __restrict__ emb, float* __restrict__ t_ws,
                       unsigned short* __restrict__ e16,
                       unsigned short* __restrict__ wsb) {
  int code = blockIdx.x * 256 + threadIdx.x;
  if (code >= KCODES) return;
  const float* e = emb + (size_t)code * 64;
  float v[64];
#pragma unroll
  for (int i = 0; i < 64; ++i) v[i] = e[i];
  // exact numpy pairwise-8 norm
  float r[8];
#pragma unroll
  for (int j = 0; j < 8; ++j) r[j] = __fmul_rn(v[j], v[j]);
#pragma unroll
  for (int m = 1; m < 8; ++m)
#pragma unroll
    for (int j = 0; j < 8; ++j) r[j] = __fadd_rn(r[j], __fmul_rn(v[m * 8 + j], v[m * 8 + j]));
  t_ws[code] = __fadd_rn(__fadd_rn(__fadd_rn(r[0], r[1]), __fadd_rn(r[2], r[3])),
                         __fadd_rn(__fadd_rn(r[4], r[5]), __fadd_rn(r[6], r[7])));
  const int ct = code >> 4, col = code & 15;
#pragma unroll
  for (int h = 0; h < 2; ++h) {
#pragma unroll
    for (int kg = 0; kg < 4; ++kg) {
      s16x8_t c0, c1, c2;
#pragma unroll
      for (int j = 0; j < 8; ++j) {
        float x = v[h * 32 + kg * 8 + j];
        unsigned short b0 = f2bf(x);
        float r1 = __fsub_rn(x, bf2f(b0));
        unsigned short b1 = f2bf(r1);
        float r2 = __fsub_rn(r1, bf2f(b1));
        unsigned short b2 = f2bf(r2);
        c0[j] = (short)b0; c1[j] = (short)b1; c2[j] = (short)b2;
      }
      *(s16x8_t*)(e16 + (size_t)code * 64 + h * 32 + kg * 8) = c0;
      size_t base = ((size_t)(ct * 6 + h) * 64 + kg * 16 + col) * 8;
      *(s16x8_t*)(wsb + base) = c0;                       // s=0
      *(s16x8_t*)(wsb + base + (size_t)2 * 64 * 8) = c1;  // s=1
      *(s16x8_t*)(wsb + base + (size_t)4 * 64 * 8) = c2;  // s=2
    }
  }
}

// ---- K0b: per-row |k|^2 exact pairwise-8 ----
__global__ void vq_prek(const float* __restrict__ keys, float* __restrict__ s_ws) {
  int row = blockIdx.x * 256 + threadIdx.x;
  const float* p = keys + (size_t)row * 64;
  float v[64];
#pragma unroll
  for (int i = 0; i < 64; ++i) v[i] = p[i];
  float r[8];
#pragma unroll
  for (int j = 0; j < 8; ++j) r[j] = __fmul_rn(v[j], v[j]);
#pragma unroll
  for (int m = 1; m < 8; ++m)
#pragma unroll
    for (int j = 0; j < 8; ++j) r[j] = __fadd_rn(r[j], __fmul_rn(v[m * 8 + j], v[m * 8 + j]));
  s_ws[row] = __fadd_rn(__fadd_rn(__fadd_rn(r[0], r[1]), __fadd_rn(r[2], r[3])),
                        __fadd_rn(__fadd_rn(r[4], r[5]), __fadd_rn(r[6], r[7])));
}

// ---- K1: lse[n] via bf16 MFMA GEMM + fused row-sumexp (unchanged R1) ----
__global__ __launch_bounds__(256) void vq_lse(const float* __restrict__ keys,
                                              const unsigned short* __restrict__ e16,
                                              const float* __restrict__ t_ws,
                                              float* __restrict__ lse_ws) {
  const int tid = threadIdx.x;
  const int w = tid >> 6, lane = tid & 63;
  const int r0 = blockIdx.x * 64 + w * 16;
  const int mrow = lane & 15, kg = lane >> 4;

  const float* ka = keys + (size_t)(r0 + mrow) * 64 + kg * 8;
  float av[16];
#pragma unroll
  for (int i = 0; i < 8; ++i) av[i] = ka[i];
#pragma unroll
  for (int i = 0; i < 8; ++i) av[8 + i] = ka[32 + i];
  float sp = 0.f;
#pragma unroll
  for (int i = 0; i < 16; ++i) sp = fmaf(av[i], av[i], sp);
  sp += __shfl_xor(sp, 16);
  sp += __shfl_xor(sp, 32);

  s16x8_t a0, a1;
#pragma unroll
  for (int i = 0; i < 8; ++i) { a0[i] = (short)f2bf(av[i]); a1[i] = (short)f2bf(av[8 + i]); }

  float S0 = 0.f, S1 = 0.f, S2 = 0.f, S3 = 0.f;
  for (int ct = 0; ct < 256; ++ct) {
    const int col = ct * 16 + mrow;
    const s16x8_t b0 = *(const s16x8_t*)(e16 + (size_t)col * 64 + kg * 8);
    const s16x8_t b1 = *(const s16x8_t*)(e16 + (size_t)col * 64 + 32 + kg * 8);
    f32x4_t acc = {0.f, 0.f, 0.f, 0.f};
    acc = __builtin_amdgcn_mfma_f32_16x16x32_bf16(a0, b0, acc, 0, 0, 0);
    acc = __builtin_amdgcn_mfma_f32_16x16x32_bf16(a1, b1, acc, 0, 0, 0);
    const float tc = t_ws[col];
    S0 += __expf(2.f * acc[0] - tc);
    S1 += __expf(2.f * acc[1] - tc);
    S2 += __expf(2.f * acc[2] - tc);
    S3 += __expf(2.f * acc[3] - tc);
  }
#pragma unroll
  for (int m = 1; m <= 8; m <<= 1) {
    S0 += __shfl_xor(S0, m); S1 += __shfl_xor(S1, m);
    S2 += __shfl_xor(S2, m); S3 += __shfl_xor(S3, m);
  }
  float s0 = __shfl(sp, kg * 4 + 0);
  float s1 = __shfl(sp, kg * 4 + 1);
  float s2 = __shfl(sp, kg * 4 + 2);
  float s3 = __shfl(sp, kg * 4 + 3);
  if (mrow == 0) {
    lse_ws[r0 + kg * 4 + 0] = logf(S0) - s0;
    lse_ws[r0 + kg * 4 + 1] = logf(S1) - s1;
    lse_ws[r0 + kg * 4 + 2] = logf(S2) - s2;
    lse_ws[r0 + kg * 4 + 3] = logf(S3) - s3;
  }
}

// ---- K2: split-bf16 MFMA logits + gumbel argmax + outputs ----
// wave = rows [nlo..nlo+16) and [nhi..nhi+16), nhi = nlo+32768 (threefry pair).
// A frag: row = lane&15, k = (lane>>4)*8+j (+32 for h=1).
// D frag: col = lane&15, row = (lane>>4)*4 + reg.
#define TERM(sa, sb)                                                             \
  accL = __builtin_amdgcn_mfma_f32_16x16x32_bf16(aL[sa][0], B[(sb)*2+0], accL, 0, 0, 0); \
  accH = __builtin_amdgcn_mfma_f32_16x16x32_bf16(aH[sa][0], B[(sb)*2+0], accH, 0, 0, 0); \
  accL = __builtin_amdgcn_mfma_f32_16x16x32_bf16(aL[sa][1], B[(sb)*2+1], accL, 0, 0, 0); \
  accH = __builtin_amdgcn_mfma_f32_16x16x32_bf16(aH[sa][1], B[(sb)*2+1], accH, 0, 0, 0);

__global__ __launch_bounds__(256, 3) void vq_main2(
    const float* __restrict__ keys, const float* __restrict__ emb,
    const float* __restrict__ t_ws, const float* __restrict__ s_ws,
    const float* __restrict__ lse_ws, const unsigned short* __restrict__ wsb,
    float* __restrict__ out) {
  const int tid = threadIdx.x;
  const int lane = tid & 63;
  const int wid = blockIdx.x * 4 + (tid >> 6);
  const int r16 = lane & 15;  // A-row-in-tile == D-col-in-tile
  const int kg = lane >> 4;
  const int nlo = wid * 16, nhi = nlo + NPAIR;

  // load + exact 3-way split of A fragments (both row blocks)
  s16x8_t aL[3][2], aH[3][2];
  {
    const float* pL = keys + (size_t)(nlo + r16) * 64 + kg * 8;
    const float* pH = keys + (size_t)(nhi + r16) * 64 + kg * 8;
#pragma unroll
    for (int h = 0; h < 2; ++h) {
#pragma unroll
      for (int j = 0; j < 8; ++j) {
        float x = pL[h * 32 + j];
        unsigned short b0 = f2bf(x);
        float r1 = __fsub_rn(x, bf2f(b0));
        unsigned short b1 = f2bf(r1);
        float r2 = __fsub_rn(r1, bf2f(b1));
        aL[0][h][j] = (short)b0; aL[1][h][j] = (short)b1; aL[2][h][j] = (short)f2bf(r2);
        x = pH[h * 32 + j];
        b0 = f2bf(x); r1 = __fsub_rn(x, bf2f(b0)); b1 = f2bf(r1);
        r2 = __fsub_rn(r1, bf2f(b1));
        aH[0][h][j] = (short)b0; aH[1][h][j] = (short)b1; aH[2][h][j] = (short)f2bf(r2);
      }
    }
  }

  // per-lane row constants for rows kg*4+reg
  float sL[4], sH[4], lseL[4], lseH[4];
  uint32_t obL[4], obH[4];  // n*4096 + r16 : output offset AND threefry base
#pragma unroll
  for (int r = 0; r < 4; ++r) {
    sL[r] = s_ws[nlo + kg * 4 + r];
    sH[r] = s_ws[nhi + kg * 4 + r];
    lseL[r] = lse_ws[nlo + kg * 4 + r];
    lseH[r] = lse_ws[nhi + kg * 4 + r];
    obL[r] = (uint32_t)(nlo + kg * 4 + r) * 4096u + (uint32_t)r16;
    obH[r] = (uint32_t)(nhi + kg * 4 + r) * 4096u + (uint32_t)r16;
  }

  float bestL[4], bestH[4];
  int biL[4], biH[4];
#pragma unroll
  for (int r = 0; r < 4; ++r) {
    bestL[r] = bestH[r] = -__builtin_inff();
    biL[r] = biH[r] = 0;
  }

  float* outLP = out + LP_OFF;
  const s16x8_t* bp = (const s16x8_t*)wsb + lane;

  s16x8_t B[6];
#pragma unroll
  for (int f = 0; f < 6; ++f) B[f] = bp[f * 64];

  for (int ct = 0; ct < 256; ++ct) {
    f32x4_t accL = {0.f, 0.f, 0.f, 0.f}, accH = {0.f, 0.f, 0.f, 0.f};
    // small terms first; two independent chains (L/H) interleaved
    TERM(1, 1) TERM(2, 0) TERM(0, 2) TERM(1, 0) TERM(0, 1) TERM(0, 0)

    const float tk = t_ws[ct * 16 + r16];
    if (ct < 255) {  // prefetch next tile's B frags; latency hidden by epilogue
      bp += 6 * 64;
#pragma unroll
      for (int f = 0; f < 6; ++f) B[f] = bp[f * 64];
    }

#pragma unroll
    for (int r = 0; r < 4; ++r) {
      const uint32_t j = obL[r] + (uint32_t)(ct * 16);
      uint32_t o0, o1;
      threefry(j, j + 0x08000000u, o0, o1);
      const float lL = __fsub_rn(__fsub_rn(__fmul_rn(2.0f, accL[r]), sL[r]), tk);
      const float lH = __fsub_rn(__fsub_rn(__fmul_rn(2.0f, accH[r]), sH[r]), tk);
      const float vL = __fadd_rn(lL, gumbel_bits(o0));
      const float vH = __fadd_rn(lH, gumbel_bits(o1));
      const int k = ct * 16 + r16;
      if (vL > bestL[r]) { bestL[r] = vL; biL[r] = k; }
      if (vH > bestH[r]) { bestH[r] = vH; biH[r] = k; }
      outLP[(size_t)obL[r] + (size_t)(ct * 16)] = __fsub_rn(lL, lseL[r]);
      outLP[(size_t)obH[r] + (size_t)(ct * 16)] = __fsub_rn(lH, lseH[r]);
    }
  }

  // argmax reduce across the 16 lanes of each kg group (first-index tiebreak)
#pragma unroll
  for (int r = 0; r < 4; ++r) {
#pragma unroll
    for (int m = 1; m <= 8; m <<= 1) {
      float ov = __shfl_xor(bestL[r], m);
      int oi = __shfl_xor(biL[r], m);
      if (ov > bestL[r] || (ov == bestL[r] && oi < biL[r])) { bestL[r] = ov; biL[r] = oi; }
      ov = __shfl_xor(bestH[r], m);
      oi = __shfl_xor(biH[r], m);
      if (ov > bestH[r] || (ov == bestH[r] && oi < biH[r])) { bestH[r] = ov; biH[r] = oi; }
    }
  }

  // samples = k + (q - k), exact op order; 16 lanes x float4 per row
#pragma unroll
  for (int r = 0; r < 4; ++r) {
    {
      const int row = nlo + kg * 4 + r;
      const float4 qq = *(const float4*)(emb + (size_t)biL[r] * 64 + r16 * 4);
      const float4 kv = *(const float4*)(keys + (size_t)row * 64 + r16 * 4);
      float4 rr;
      rr.x = __fadd_rn(kv.x, __fsub_rn(qq.x, kv.x));
      rr.y = __fadd_rn(kv.y, __fsub_rn(qq.y, kv.y));
      rr.z = __fadd_rn(kv.z, __fsub_rn(qq.z, kv.z));
      rr.w = __fadd_rn(kv.w, __fsub_rn(qq.w, kv.w));
      *(float4*)(out + (size_t)row * 64 + r16 * 4) = rr;
    }
    {
      const int row = nhi + kg * 4 + r;
      const float4 qq = *(const float4*)(emb + (size_t)biH[r] * 64 + r16 * 4);
      const float4 kv = *(const float4*)(keys + (size_t)row * 64 + r16 * 4);
      float4 rr;
      rr.x = __fadd_rn(kv.x, __fsub_rn(qq.x, kv.x));
      rr.y = __fadd_rn(kv.y, __fsub_rn(qq.y, kv.y));
      rr.z = __fadd_rn(kv.z, __fsub_rn(qq.z, kv.z));
      rr.w = __fadd_rn(kv.w, __fsub_rn(qq.w, kv.w));
      *(float4*)(out + (size_t)row * 64 + r16 * 4) = rr;
    }
  }
}

extern "C" void kernel_launch(void* const* d_in, const int* in_sizes, int n_in,
                              void* d_out, int out_size, void* d_ws, size_t ws_size,
                              hipStream_t stream) {
  const float* keys = (const float*)d_in[0];
  const float* emb = (const float*)d_in[1];
  float* out = (float*)d_out;
  char* w = (char*)d_ws;
  float* t_ws = (float*)(w + WS_T);
  float* s_ws = (float*)(w + WS_S);
  float* lse_ws = (float*)(w + WS_LSE);
  unsigned short* e16 = (unsigned short*)(w + WS_E16);
  unsigned short* wsb = (unsigned short*)(w + WS_B);

  vq_pre<<<16, 256, 0, stream>>>(emb, t_ws, e16, wsb);
  vq_prek<<<256, 256, 0, stream>>>(keys, s_ws);
  vq_lse<<<1024, 256, 0, stream>>>(keys, e16, t_ws, lse_ws);
  vq_main2<<<512, 256, 0, stream>>>(keys, emb, t_ws, s_ws, lse_ws, wsb, out);
}